// Round 1
// baseline (698.497 us; speedup 1.0000x reference)
//
#include <hip/hip_runtime.h>
#include <math.h>

// Problem constants (fixed by reference setup_inputs)
constexpr int B = 4, H = 8, N = 2048, C = 512;
constexpr float TAU = 1.5f;
constexpr int MIN_TOKENS = 32;
constexpr float EPS = 1e-6f;

// ---------------------------------------------------------------------------
// Kernel 1: per-(b,i) row entropy of head-mean attention.
// One block per (b,i). 256 threads, float4 loads: 2 iters * 4 floats = 8 j's
// per thread, 8 heads each -> 64 float loads/thread, fully coalesced per head.
// Reads 512 MiB total exactly once -> memory-bound streaming.
// ---------------------------------------------------------------------------
__global__ __launch_bounds__(256) void entropy_kernel(
    const float* __restrict__ attn, float* __restrict__ ent_out) {
    const int bi = blockIdx.x;          // b*N + i
    const int b  = bi >> 11;            // / N
    const int i  = bi & (N - 1);
    const int t  = threadIdx.x;

    const float* base = attn + ((size_t)(b * H) * N + i) * (size_t)N;
    const size_t hstride = (size_t)N * N;

    float ent = 0.f;
#pragma unroll
    for (int iter = 0; iter < 2; ++iter) {
        const int j = iter * 1024 + t * 4;
        float4 s = make_float4(0.f, 0.f, 0.f, 0.f);
#pragma unroll
        for (int h = 0; h < H; ++h) {
            const float4 v =
                *reinterpret_cast<const float4*>(base + h * hstride + j);
            s.x += v.x; s.y += v.y; s.z += v.z; s.w += v.w;
        }
        float p;
        p = s.x * 0.125f; ent += p * logf(p + EPS);
        p = s.y * 0.125f; ent += p * logf(p + EPS);
        p = s.z * 0.125f; ent += p * logf(p + EPS);
        p = s.w * 0.125f; ent += p * logf(p + EPS);
    }

    // block reduce (4 waves of 64)
#pragma unroll
    for (int off = 32; off > 0; off >>= 1) ent += __shfl_down(ent, off, 64);
    __shared__ float ws[4];
    const int wid = t >> 6, lane = t & 63;
    if (lane == 0) ws[wid] = ent;
    __syncthreads();
    if (t == 0) ent_out[bi] = -(ws[0] + ws[1] + ws[2] + ws[3]);
}

// ---------------------------------------------------------------------------
// Kernel 2: per-batch selection. One block per batch, 256 threads.
//  - count = #(entropy > TAU)
//  - if count >= MIN_TOKENS: stable compaction (original order) via block scan
//  - else: 32 x block-argmax top-k (value desc, tie -> lower index, matching
//          jax.lax.top_k), writing indices in entropy-descending order
// ---------------------------------------------------------------------------
__global__ __launch_bounds__(256) void select_kernel(
    const float* __restrict__ ent, int* __restrict__ idx_out,
    int* __restrict__ keep_out) {
    const int b = blockIdx.x;
    const int t = threadIdx.x;

    __shared__ float vals[N];      // 8 KB
    __shared__ int   cnts[256];
    __shared__ float red_v[4];
    __shared__ int   red_i[4];

    for (int k = t; k < N; k += 256) vals[k] = ent[b * N + k];
    __syncthreads();

    // each thread owns 8 consecutive elements [t*8, t*8+8)
    int local = 0;
#pragma unroll
    for (int u = 0; u < 8; ++u) local += (vals[t * 8 + u] > TAU) ? 1 : 0;
    cnts[t] = local;
    __syncthreads();

    // Hillis-Steele inclusive scan over 256 per-thread counts
    for (int off = 1; off < 256; off <<= 1) {
        const int v   = cnts[t];
        const int add = (t >= off) ? cnts[t - off] : 0;
        __syncthreads();
        cnts[t] = v + add;
        __syncthreads();
    }
    const int total = cnts[255];

    if (total >= MIN_TOKENS) {
        // stable compaction: kept indices first, original order
        int pos = cnts[t] - local;  // exclusive prefix
#pragma unroll
        for (int u = 0; u < 8; ++u) {
            const int k = t * 8 + u;
            if (vals[k] > TAU) idx_out[b * N + pos++] = k;
        }
        if (t == 0) keep_out[b] = total;
    } else {
        // top-k fallback: 32 iterations of block argmax
        for (int k = 0; k < MIN_TOKENS; ++k) {
            float bv = -INFINITY; int bj = 0;
#pragma unroll
            for (int u = 0; u < 8; ++u) {
                const int j = t * 8 + u;
                const float v = vals[j];
                if (v > bv) { bv = v; bj = j; }
            }
#pragma unroll
            for (int off = 32; off > 0; off >>= 1) {
                const float ov = __shfl_down(bv, off, 64);
                const int   oj = __shfl_down(bj, off, 64);
                if (ov > bv || (ov == bv && oj < bj)) { bv = ov; bj = oj; }
            }
            const int wid = t >> 6, lane = t & 63;
            if (lane == 0) { red_v[wid] = bv; red_i[wid] = bj; }
            __syncthreads();
            if (t == 0) {
                float fv = red_v[0]; int fj = red_i[0];
#pragma unroll
                for (int w = 1; w < 4; ++w) {
                    if (red_v[w] > fv || (red_v[w] == fv && red_i[w] < fj)) {
                        fv = red_v[w]; fj = red_i[w];
                    }
                }
                idx_out[b * N + k] = fj;
                vals[fj] = -INFINITY;   // exclude from next iteration
            }
            __syncthreads();
        }
        if (t == 0) keep_out[b] = MIN_TOKENS;
    }
}

// ---------------------------------------------------------------------------
// Kernel 3: gather + zero-pad. One block per output row (b,r); 128 threads
// move 128 float4 = 512 floats. Rows >= keep_len[b] are zeroed (d_out is
// poisoned 0xAA before every launch).
// ---------------------------------------------------------------------------
__global__ __launch_bounds__(128) void gather_kernel(
    const float* __restrict__ tokens, const int* __restrict__ idx,
    const int* __restrict__ keep, float* __restrict__ out) {
    const int br = blockIdx.x;          // b*N + r
    const int b  = br >> 11;
    const int r  = br & (N - 1);
    const int t  = threadIdx.x;

    float4* orow = reinterpret_cast<float4*>(out + (size_t)br * C);
    if (r < keep[b]) {
        const int src = idx[br];
        const float4* srow = reinterpret_cast<const float4*>(
            tokens + ((size_t)b * N + src) * (size_t)C);
        orow[t] = srow[t];
    } else {
        orow[t] = make_float4(0.f, 0.f, 0.f, 0.f);
    }
}

extern "C" void kernel_launch(void* const* d_in, const int* in_sizes, int n_in,
                              void* d_out, int out_size, void* d_ws, size_t ws_size,
                              hipStream_t stream) {
    const float* tokens = (const float*)d_in[0];  // (B, N, C) f32
    const float* attn   = (const float*)d_in[1];  // (B, H, N, N) f32
    float* out = (float*)d_out;                   // (B, N, C) f32

    // workspace layout: entropy (B*N f32) | idx (B*N i32) | keep (B i32)
    float* ent_ws  = (float*)d_ws;
    int*   idx_ws  = (int*)((char*)d_ws + (size_t)B * N * sizeof(float));
    int*   keep_ws = (int*)((char*)d_ws + 2 * (size_t)B * N * sizeof(float));

    entropy_kernel<<<B * N, 256, 0, stream>>>(attn, ent_ws);
    select_kernel<<<B, 256, 0, stream>>>(ent_ws, idx_ws, keep_ws);
    gather_kernel<<<B * N, 128, 0, stream>>>(tokens, idx_ws, keep_ws, out);
}